// Round 1
// baseline (98.141 us; speedup 1.0000x reference)
//
#include <hip/hip_runtime.h>

typedef float f32x4 __attribute__((ext_vector_type(4)));
typedef short s16x8 __attribute__((ext_vector_type(8)));

#define B_SZ   4096
#define C_N    64
#define D_K    512
#define H_N    1024
#define HT     8        // h-blocks per company
#define HB     128      // h per block (4 waves x 32)
#define SCHUNK 64       // samples per super-chunk (4 M-frags of 16)
#define KSTEPS 16       // 512 / 32

__device__ __forceinline__ short f2bf(float f){
  unsigned u = __float_as_uint(f);
  u += 0x7FFFu + ((u >> 16) & 1u);   // RTNE
  return (short)(u >> 16);
}
__device__ __forceinline__ float gelu_exact(float x){
  return 0.5f * x * (1.0f + erff(x * 0.70710678118654752f));
}

__global__ void k_count(const int* __restrict__ cid, int* __restrict__ counts){
  int i = blockIdx.x * 256 + threadIdx.x;
  if (i < B_SZ) atomicAdd(&counts[cid[i]], 1);
}

__global__ void k_scan(const int* __restrict__ counts, int* __restrict__ offsets,
                       int* __restrict__ cursor){
  int l = threadIdx.x;              // 64 threads = 1 wave
  int v = counts[l];
  int x = v;
  #pragma unroll
  for (int d = 1; d < 64; d <<= 1){
    int y = __shfl_up(x, d, 64);
    if (l >= d) x += y;
  }
  offsets[l] = x - v;
  cursor[l]  = x - v;
  if (l == 63) offsets[64] = x;
}

__global__ void k_scatter(const int* __restrict__ cid, const float* __restrict__ b2,
                          int* __restrict__ cursor, int* __restrict__ bucket,
                          float* __restrict__ out){
  int i = blockIdx.x * 256 + threadIdx.x;
  if (i < B_SZ){
    int c = cid[i];
    int pos = atomicAdd(&cursor[c], 1);
    bucket[pos] = i;
    out[i] = b2[c];                 // initialize output with bias2
  }
}

__global__ __launch_bounds__(256) void k_main(
    const float* __restrict__ z, const float* __restrict__ W1,
    const float* __restrict__ b1, const float* __restrict__ W2,
    const int* __restrict__ offsets, const int* __restrict__ bucket,
    float* __restrict__ out)
{
  __shared__ s16x8 A_lds[SCHUNK * D_K / 8];   // 64 KiB, frag-ordered bf16
  const int c  = blockIdx.x;                  // same-c blocks -> same XCD
  const int ht = blockIdx.y;
  const int off_c = offsets[c], end_c = offsets[c + 1];
  if (end_c == off_c) return;
  const int n_c = end_c - off_c;

  const int tid  = threadIdx.x;
  const int lane = tid & 63, wave = tid >> 6;
  const int l15 = lane & 15, l4 = lane >> 4;
  const int h0 = ht * HB + wave * 32;
  const float* Wc = W1 + (size_t)c * D_K * H_N;

  const int h_a = c * H_N + h0 + l15;
  const float b1v0 = b1[h_a],      b1v1 = b1[h_a + 16];
  const float w2v0 = W2[h_a],      w2v1 = W2[h_a + 16];

  const int nsc = (n_c + SCHUNK - 1) / SCHUNK;
  for (int scn = 0; scn < nsc; ++scn){
    const int base_slot = off_c + scn * SCHUNK;
    __syncthreads();
    // ---- stage 64 sample rows x 512 K as bf16, MFMA-frag order ----
    #pragma unroll
    for (int i = 0; i < 16; ++i){
      int unit  = tid + 256 * i;          // contiguous LDS write: conflict-free
      int row16 = unit & 15;
      int koff  = (unit >> 4) & 3;
      int ks    = (unit >> 6) & 15;
      int m     = unit >> 10;
      int r     = m * 16 + row16;
      int o     = ks * 4 + koff;          // k-octet: k = o*8 .. o*8+7
      int slot  = base_slot + r;
      float4 a = make_float4(0.f,0.f,0.f,0.f), b = make_float4(0.f,0.f,0.f,0.f);
      if (slot < end_c){
        const float* zp = z + (size_t)bucket[slot] * D_K + o * 8;
        a = *(const float4*)zp;
        b = *(const float4*)(zp + 4);
      }
      s16x8 v;
      v[0]=f2bf(a.x); v[1]=f2bf(a.y); v[2]=f2bf(a.z); v[3]=f2bf(a.w);
      v[4]=f2bf(b.x); v[5]=f2bf(b.y); v[6]=f2bf(b.z); v[7]=f2bf(b.w);
      A_lds[unit] = v;
    }
    __syncthreads();

    f32x4 acc[4][2];
    #pragma unroll
    for (int m = 0; m < 4; ++m){ acc[m][0] = 0; acc[m][1] = 0; }

    for (int ks = 0; ks < KSTEPS; ++ks){
      // B frags straight from global f32 (each element used exactly once here)
      const float* bp = Wc + (size_t)(ks * 32 + l4 * 8) * H_N + h0 + l15;
      s16x8 bf0, bf1;
      #pragma unroll
      for (int e = 0; e < 8; ++e){
        bf0[e] = f2bf(bp[e * H_N]);
        bf1[e] = f2bf(bp[e * H_N + 16]);
      }
      #pragma unroll
      for (int m = 0; m < 4; ++m){
        s16x8 af = A_lds[(m * 16 + ks) * 64 + lane];
        acc[m][0] = __builtin_amdgcn_mfma_f32_16x16x32_bf16(af, bf0, acc[m][0], 0, 0, 0);
        acc[m][1] = __builtin_amdgcn_mfma_f32_16x16x32_bf16(af, bf1, acc[m][1], 0, 0, 0);
      }
    }

    // ---- epilogue: GELU(acc + b1) * W2, reduce 32 h per wave, atomic to out ----
    #pragma unroll
    for (int m = 0; m < 4; ++m){
      #pragma unroll
      for (int r = 0; r < 4; ++r){
        float s = gelu_exact(acc[m][0][r] + b1v0) * w2v0
                + gelu_exact(acc[m][1][r] + b1v1) * w2v1;
        s += __shfl_xor(s, 1, 64);
        s += __shfl_xor(s, 2, 64);
        s += __shfl_xor(s, 4, 64);
        s += __shfl_xor(s, 8, 64);
        int slot = base_slot + m * 16 + l4 * 4 + r;
        if (l15 == 0 && slot < end_c){
          atomicAdd(&out[bucket[slot]], s);
        }
      }
    }
  }
}

extern "C" void kernel_launch(void* const* d_in, const int* in_sizes, int n_in,
                              void* d_out, int out_size, void* d_ws, size_t ws_size,
                              hipStream_t stream){
  const float* z  = (const float*)d_in[0];
  const int*   cid= (const int*)  d_in[1];
  const float* W1 = (const float*)d_in[2];
  const float* b1 = (const float*)d_in[3];
  const float* W2 = (const float*)d_in[4];
  const float* b2 = (const float*)d_in[5];
  float* out = (float*)d_out;

  int* ws      = (int*)d_ws;
  int* counts  = ws;          // [64]
  int* offsets = ws + 64;     // [65]
  int* cursor  = ws + 192;    // [64]
  int* bucket  = ws + 256;    // [4096]

  hipMemsetAsync(counts, 0, 64 * sizeof(int), stream);
  k_count  <<<(B_SZ + 255) / 256, 256, 0, stream>>>(cid, counts);
  k_scan   <<<1, 64, 0, stream>>>(counts, offsets, cursor);
  k_scatter<<<(B_SZ + 255) / 256, 256, 0, stream>>>(cid, b2, cursor, bucket, out);
  dim3 grid(C_N, HT);
  k_main   <<<grid, 256, 0, stream>>>(z, W1, b1, W2, offsets, bucket, out);
}

// Round 2
// 94.961 us; speedup vs baseline: 1.0335x; 1.0335x over previous
//
#include <hip/hip_runtime.h>

typedef float f32x4 __attribute__((ext_vector_type(4)));
typedef short s16x8 __attribute__((ext_vector_type(8)));

#define B_SZ   4096
#define C_N    64
#define D_K    512
#define H_N    1024
#define HT     8        // h-blocks per company
#define HB     128      // h per block (8 waves x 16)
#define SCHUNK 64       // samples per chunk (4 M-frags of 16)
#define KSTEPS 16       // 512 / 32
#define MAXCHUNKS 127   // sum ceil(n_c/64) <= 64 + 63

__device__ __forceinline__ short f2bf(float f){
  unsigned u = __float_as_uint(f);
  u += 0x7FFFu + ((u >> 16) & 1u);   // RTNE
  return (short)(u >> 16);
}
__device__ __forceinline__ float gelu_exact(float x){
  return 0.5f * x * (1.0f + erff(x * 0.70710678118654752f));
}

__global__ void k_count(const int* __restrict__ cid, int* __restrict__ counts){
  int i = blockIdx.x * 256 + threadIdx.x;
  if (i < B_SZ) atomicAdd(&counts[cid[i]], 1);
}

__global__ void k_scan(const int* __restrict__ counts, int* __restrict__ offsets,
                       int* __restrict__ cursor, int* __restrict__ chunk_table,
                       int* __restrict__ nchunks){
  int l = threadIdx.x;              // 64 threads = 1 wave
  int v = counts[l];
  int x = v;
  #pragma unroll
  for (int d = 1; d < 64; d <<= 1){
    int y = __shfl_up(x, d, 64);
    if (l >= d) x += y;
  }
  offsets[l] = x - v;
  cursor[l]  = x - v;
  if (l == 63) offsets[64] = x;
  // chunk table: one entry per (company, chunk-within-company)
  int nch = (v + SCHUNK - 1) / SCHUNK;
  int cx = nch;
  #pragma unroll
  for (int d = 1; d < 64; d <<= 1){
    int y = __shfl_up(cx, d, 64);
    if (l >= d) cx += y;
  }
  int cbase = cx - nch;
  for (int j = 0; j < nch; ++j) chunk_table[cbase + j] = (l << 8) | j;
  if (l == 63) nchunks[0] = cx;
}

__global__ void k_scatter(const int* __restrict__ cid, const float* __restrict__ b2,
                          int* __restrict__ cursor, int* __restrict__ bucket,
                          float* __restrict__ out){
  int i = blockIdx.x * 256 + threadIdx.x;
  if (i < B_SZ){
    int c = cid[i];
    int pos = atomicAdd(&cursor[c], 1);
    bucket[pos] = i;
    out[i] = b2[c];                 // initialize output with bias2
  }
}

__global__ __launch_bounds__(512, 4) void k_main(
    const float* __restrict__ z, const float* __restrict__ W1,
    const float* __restrict__ b1, const float* __restrict__ W2,
    const int* __restrict__ offsets, const int* __restrict__ bucket,
    const int* __restrict__ chunk_table, const int* __restrict__ nchunks,
    float* __restrict__ out)
{
  __shared__ s16x8 A_lds[SCHUNK * D_K / 8];   // 64 KiB, frag-ordered bf16
  const int ci = blockIdx.x;
  if (ci >= nchunks[0]) return;
  const int entry = chunk_table[ci];
  const int c = entry >> 8, j = entry & 255;
  const int base_slot = offsets[c] + j * SCHUNK;
  const int end_c = offsets[c + 1];

  const int ht = blockIdx.y;
  const int tid  = threadIdx.x;
  const int lane = tid & 63, wave = tid >> 6;      // 8 waves
  const int l15 = lane & 15, l4 = lane >> 4;
  const int h0 = ht * HB + wave * 16;              // 16 h per wave
  const float* Wc = W1 + (size_t)c * D_K * H_N;

  const int h_a = c * H_N + h0 + l15;
  const float b1v = b1[h_a];
  const float w2v = W2[h_a];

  // ---- stage 64 sample rows x 512 K as bf16, MFMA-frag order ----
  #pragma unroll
  for (int i = 0; i < 8; ++i){
    int unit  = tid + 512 * i;          // contiguous LDS write: conflict-free
    int row16 = unit & 15;
    int koff  = (unit >> 4) & 3;
    int ks    = (unit >> 6) & 15;
    int m     = unit >> 10;
    int r     = m * 16 + row16;
    int o     = ks * 4 + koff;          // k-octet: k = o*8 .. o*8+7
    int slot  = base_slot + r;
    float4 a = make_float4(0.f,0.f,0.f,0.f), b = make_float4(0.f,0.f,0.f,0.f);
    if (slot < end_c){
      const float* zp = z + (size_t)bucket[slot] * D_K + o * 8;
      a = *(const float4*)zp;
      b = *(const float4*)(zp + 4);
    }
    s16x8 v;
    v[0]=f2bf(a.x); v[1]=f2bf(a.y); v[2]=f2bf(a.z); v[3]=f2bf(a.w);
    v[4]=f2bf(b.x); v[5]=f2bf(b.y); v[6]=f2bf(b.z); v[7]=f2bf(b.w);
    A_lds[unit] = v;
  }
  __syncthreads();

  // ---- W1 inner loop: 4-step rolling prefetch pipeline ----
  const float* bp_base = Wc + (size_t)(l4 * 8) * H_N + h0 + l15;

  float fb[4][8];                     // 4 pipeline slots x 8 k-elems (fully unrolled -> regs)
  #pragma unroll
  for (int s = 0; s < 4; ++s){
    #pragma unroll
    for (int e = 0; e < 8; ++e)
      fb[s][e] = bp_base[(size_t)(s * 32 + e) * H_N];
  }

  f32x4 acc[4];
  #pragma unroll
  for (int m = 0; m < 4; ++m) acc[m] = 0;

  #pragma unroll
  for (int ks = 0; ks < KSTEPS; ++ks){
    const int sl = ks & 3;
    s16x8 bf;
    #pragma unroll
    for (int e = 0; e < 8; ++e) bf[e] = f2bf(fb[sl][e]);
    #pragma unroll
    for (int m = 0; m < 4; ++m){
      s16x8 af = A_lds[(m * 16 + ks) * 64 + lane];
      acc[m] = __builtin_amdgcn_mfma_f32_16x16x32_bf16(af, bf, acc[m], 0, 0, 0);
    }
    if (ks < KSTEPS - 4){
      #pragma unroll
      for (int e = 0; e < 8; ++e)
        fb[sl][e] = bp_base[(size_t)((ks + 4) * 32 + e) * H_N];
    }
  }

  // ---- epilogue: GELU(acc + b1) * W2, reduce 16 h per wave, atomic to out ----
  #pragma unroll
  for (int m = 0; m < 4; ++m){
    #pragma unroll
    for (int r = 0; r < 4; ++r){
      float s = gelu_exact(acc[m][r] + b1v) * w2v;
      s += __shfl_xor(s, 1, 64);
      s += __shfl_xor(s, 2, 64);
      s += __shfl_xor(s, 4, 64);
      s += __shfl_xor(s, 8, 64);
      int slot = base_slot + m * 16 + l4 * 4 + r;
      if (l15 == 0 && slot < end_c){
        atomicAdd(&out[bucket[slot]], s);
      }
    }
  }
}

extern "C" void kernel_launch(void* const* d_in, const int* in_sizes, int n_in,
                              void* d_out, int out_size, void* d_ws, size_t ws_size,
                              hipStream_t stream){
  const float* z  = (const float*)d_in[0];
  const int*   cid= (const int*)  d_in[1];
  const float* W1 = (const float*)d_in[2];
  const float* b1 = (const float*)d_in[3];
  const float* W2 = (const float*)d_in[4];
  const float* b2 = (const float*)d_in[5];
  float* out = (float*)d_out;

  int* ws          = (int*)d_ws;
  int* counts      = ws;          // [64]
  int* offsets     = ws + 64;     // [65]
  int* cursor      = ws + 192;    // [64]
  int* chunk_table = ws + 256;    // [127]
  int* nchunks     = ws + 384;    // [1]
  int* bucket      = ws + 512;    // [4096]

  hipMemsetAsync(counts, 0, 64 * sizeof(int), stream);
  k_count  <<<(B_SZ + 255) / 256, 256, 0, stream>>>(cid, counts);
  k_scan   <<<1, 64, 0, stream>>>(counts, offsets, cursor, chunk_table, nchunks);
  k_scatter<<<(B_SZ + 255) / 256, 256, 0, stream>>>(cid, b2, cursor, bucket, out);
  dim3 grid(MAXCHUNKS, HT);
  k_main   <<<grid, 512, 0, stream>>>(z, W1, b1, W2, offsets, bucket,
                                      chunk_table, nchunks, out);
}